// Round 12
// baseline (225.662 us; speedup 1.0000x reference)
//
#include <hip/hip_runtime.h>
#include <hip/hip_bf16.h>

#define DM   1024
#define HEADS 16
#define DH    64
#define SEQ  2048
#define BATCH   2
#define LOG2E 1.44269504088896f

typedef __attribute__((ext_vector_type(8))) short short8;
typedef __attribute__((ext_vector_type(4))) short bf16x4;
typedef __attribute__((ext_vector_type(4))) float floatx4;

__device__ __forceinline__ short f2b(float f) {
    union { float f; unsigned u; } v; v.f = f;
    unsigned r = v.u + 0x7FFFu + ((v.u >> 16) & 1u);
    return (short)(r >> 16);
}

#if __has_builtin(__builtin_amdgcn_exp2f)
__device__ __forceinline__ float fexp2(float x) { return __builtin_amdgcn_exp2f(x); }
#else
__device__ __forceinline__ float fexp2(float x) { return exp2f(x); }
#endif

__device__ __forceinline__ void async_copy16(const short* gsrc, short* ldst) {
    __builtin_amdgcn_global_load_lds(
        (const __attribute__((address_space(1))) void*)gsrc,
        (__attribute__((address_space(3))) void*)ldst,
        16, 0, 0);
}

// Fused fp32->bf16 conversion of x, Wq, Wk, Wv, Wo + mask-add table (log2 domain).
__global__ __launch_bounds__(256) void cvt_all(const float* __restrict__ x,
        const float* __restrict__ wq, const float* __restrict__ wk,
        const float* __restrict__ wv, const float* __restrict__ wo,
        const float* __restrict__ mask,
        short* __restrict__ xb, short* __restrict__ wqkv, short* __restrict__ wob,
        float* __restrict__ maddg)
{
    const int b = blockIdx.x;
    if (b >= 8192) {            // mask prep: maddg = (1-mask) * (-1e5 * log2e)
        const int bb = b - 8192;
        const float* mrow = mask + (size_t)bb * SEQ;
        float* mg = maddg + (size_t)bb * SEQ;
#pragma unroll
        for (int i = 0; i < 8; ++i) {
            const int idx = threadIdx.x * 8 + i;
            mg[idx] = (1.f - mrow[idx]) * (-100000.f * LOG2E);
        }
        return;
    }
    const float* src; short* dst; int idx;
    if (b < 4096)      { src = x;  dst = xb;                idx = b; }
    else if (b < 5120) { src = wq; dst = wqkv;              idx = b - 4096; }
    else if (b < 6144) { src = wk; dst = wqkv + (1 << 20);  idx = b - 5120; }
    else if (b < 7168) { src = wv; dst = wqkv + (2 << 20);  idx = b - 6144; }
    else               { src = wo; dst = wob;               idx = b - 7168; }
    const int i = idx * 256 + threadIdx.x;
    floatx4 v = ((const floatx4*)src)[i];
    bf16x4 o;
    o.x = f2b(v.x); o.y = f2b(v.y); o.z = f2b(v.z); o.w = f2b(v.w);
    ((bf16x4*)dst)[i] = o;
}

// Fused QKV GEMM, OPERAND-SWAPPED (C^T): A=W rows (feature dir), B=x tokens.
// Lane fragment = 4 consecutive features @ fixed token -> packed bf16x4 stores.
// Q pre-scaled by 0.125*log2e. Q/K/V out in [b,h,s,dh].
__global__ __launch_bounds__(256) void gemm_qkv(const short* __restrict__ X,
        const short* __restrict__ W,
        const float* __restrict__ bq, const float* __restrict__ bk,
        const float* __restrict__ bv,
        short* __restrict__ qw, short* __restrict__ kw, short* __restrict__ vw)
{
    __shared__ short Xs[128 * 32];
    __shared__ short Ws[128 * 32];
    const int tok0 = blockIdx.x * 128;     // token tile
    const int w0   = blockIdx.y * 128;     // weight-row tile (0..3071)
    const int w = threadIdx.x >> 6, lane = threadIdx.x & 63;
    const int l16 = lane & 15, quad = lane >> 4;
    const int wm = w >> 1, wn = w & 1;
    const int lr = lane >> 2, lc = (lane & 3) * 8;

    floatx4 acc[4][4];
#pragma unroll
    for (int i = 0; i < 4; ++i)
#pragma unroll
        for (int j = 0; j < 4; ++j) acc[i][j] = (floatx4){0.f, 0.f, 0.f, 0.f};

    for (int kt = 0; kt < DM / 32; ++kt) {
        const int k0 = kt * 32;
        __syncthreads();
        async_copy16(X + (size_t)(tok0 + w * 32 + lr) * DM + k0 + lc,      &Xs[w * 1024]);
        async_copy16(X + (size_t)(tok0 + w * 32 + 16 + lr) * DM + k0 + lc, &Xs[w * 1024 + 512]);
        async_copy16(W + (size_t)(w0 + w * 32 + lr) * DM + k0 + lc,        &Ws[w * 1024]);
        async_copy16(W + (size_t)(w0 + w * 32 + 16 + lr) * DM + k0 + lc,   &Ws[w * 1024 + 512]);
        __syncthreads();

        short8 af[4], bf[4];
#pragma unroll
        for (int i = 0; i < 4; ++i)
            af[i] = *(const short8*)&Ws[(wm * 64 + i * 16 + l16) * 32 + quad * 8];
#pragma unroll
        for (int j = 0; j < 4; ++j)
            bf[j] = *(const short8*)&Xs[(wn * 64 + j * 16 + l16) * 32 + quad * 8];
#pragma unroll
        for (int i = 0; i < 4; ++i)
#pragma unroll
            for (int j = 0; j < 4; ++j)
                acc[i][j] = __builtin_amdgcn_mfma_f32_16x16x32_bf16(af[i], bf[j], acc[i][j], 0, 0, 0);
    }

    // epilogue: C^T -> row(quad*4+r)=feature, col(l16)=token; packed 8B stores
    const int t = w0 >> 10;                // 0=Q 1=K 2=V (uniform per block)
    const int wl = w0 & 1023;
    short* dst = (t == 0) ? qw : (t == 1) ? kw : vw;
    const float* bias = (t == 0) ? bq : (t == 1) ? bk : bv;
    const float mulf = (t == 0) ? (0.125f * LOG2E) : 1.0f;

#pragma unroll
    for (int i = 0; i < 4; ++i) {
        const int wr = wl + wm * 64 + i * 16 + quad * 4;   // local feature idx, mult of 4
        const floatx4 b4 = *(const floatx4*)&bias[wr];
        const int h = wr >> 6, dh = wr & 63;
#pragma unroll
        for (int j = 0; j < 4; ++j) {
            const int tok = tok0 + wn * 64 + j * 16 + l16;
            const int b = tok >> 11, s = tok & (SEQ - 1);
            bf16x4 p;
            p.x = f2b((acc[i][j][0] + b4.x) * mulf);
            p.y = f2b((acc[i][j][1] + b4.y) * mulf);
            p.z = f2b((acc[i][j][2] + b4.z) * mulf);
            p.w = f2b((acc[i][j][3] + b4.w) * mulf);
            *(bf16x4*)&dst[(((size_t)(b * HEADS + h)) * SEQ + s) * DH + dh] = p;
        }
    }
}

// v [b,h,s,dh] -> vt [b,h,dh,s], 64x64 LDS tiles (coalesced both sides)
__global__ __launch_bounds__(256) void transpose_v(const short* __restrict__ v,
                                                   short* __restrict__ vt)
{
    __shared__ short tl[64][72];
    const int st = blockIdx.x;
    const int bh = blockIdx.y;
    const int t = threadIdx.x;
    const int row = t >> 2, off = (t & 3) * 16;
    const short* vp = v + ((size_t)bh * SEQ + st * 64 + row) * DH + off;
    *(short8*)&tl[row][off]     = *(const short8*)vp;
    *(short8*)&tl[row][off + 8] = *(const short8*)(vp + 8);
    __syncthreads();
    short8 o0, o1;
#pragma unroll
    for (int j = 0; j < 8; ++j) { o0[j] = tl[off + j][row]; o1[j] = tl[off + 8 + j][row]; }
    short* op = vt + ((size_t)bh * DH + row) * SEQ + st * 64 + off;
    *(short8*)op = o0;
    *(short8*)(op + 8) = o1;
}

// Flash attention, NO-MAX softmax (p = exp2(min(s,40)), log2 domain), xor-swizzled
// packed LDS, XCD-swizzled grid, LDS-coalesced ctx epilogue. (round-11 state)
__global__ __launch_bounds__(256) void attn_kernel(const short* __restrict__ q,
        const short* __restrict__ k, const short* __restrict__ vt,
        const float* __restrict__ maddg, short* __restrict__ ctx)
{
    const int id    = blockIdx.x;
    const int qtile = id >> 5;             // id = qtile*32 + bh
    const int bh    = id & 31;
    const int bidx  = bh >> 4;
    const int wave = threadIdx.x >> 6, lane = threadIdx.x & 63;
    const int l16 = lane & 15, quad = lane >> 4;
    const int lx = l16 & 7;

    __shared__ short k_lds[64 * 64];       // [key][dh] packed+swizzled
    __shared__ short v_lds[64 * 64];       // [dh][key] packed+swizzled
    __shared__ short p_lds[4][16 * 64];    // per-wave P [qrow][key] swizzled
    __shared__ short Ct[64 * 72];          // ctx epilogue staging

    const short* kbase0 = k  + (size_t)bh * SEQ * DH;
    const short* vbase0 = vt + (size_t)bh * DH * SEQ;
    const float* mrow   = maddg + (size_t)bidx * SEQ;

    const int qrow = qtile * 64 + wave * 16 + l16;
    const short* qbase = q + ((size_t)bh * SEQ + qrow) * DH;
    short8 b_q[2];
#pragma unroll
    for (int ks = 0; ks < 2; ++ks)
        b_q[ks] = *(const short8*)(qbase + ks * 32 + quad * 8);

    floatx4 o[4];
    floatx4 l_acc = (floatx4){0.f, 0.f, 0.f, 0.f};
#pragma unroll
    for (int d = 0; d < 4; ++d) o[d] = (floatx4){0.f, 0.f, 0.f, 0.f};

    short8 ones;
#pragma unroll
    for (int j = 0; j < 8; ++j) ones[j] = (short)0x3F80;  // bf16 1.0

    int srw[2], gg[2];
#pragma unroll
    for (int i = 0; i < 2; ++i) {
        const int slot = i * 256 + wave * 64 + lane;
        srw[i] = slot >> 3;
        gg[i]  = (slot & 7) ^ (srw[i] & 7);
    }

    for (int kt = 0; kt < SEQ / 64; ++kt) {
        __syncthreads();
        {
            const short* kbase = kbase0 + (size_t)(kt * 64) * DH;
            const short* vbase = vbase0 + kt * 64;
#pragma unroll
            for (int i = 0; i < 2; ++i) {
                async_copy16(kbase + srw[i] * DH + gg[i] * 8,
                             &k_lds[(i * 256 + wave * 64) * 8]);
                async_copy16(vbase + (size_t)srw[i] * SEQ + gg[i] * 8,
                             &v_lds[(i * 256 + wave * 64) * 8]);
            }
        }
        floatx4 md[4];
#pragma unroll
        for (int nt = 0; nt < 4; ++nt)
            md[nt] = *(const floatx4*)&mrow[kt * 64 + nt * 16 + quad * 4];
        __syncthreads();

#pragma unroll
        for (int nt = 0; nt < 4; ++nt) {
            floatx4 acc = md[nt];
#pragma unroll
            for (int ks = 0; ks < 2; ++ks) {
                short8 a = *(const short8*)
                    &k_lds[(nt * 16 + l16) * 64 + (((ks * 4 + quad) ^ lx) * 8)];
                acc = __builtin_amdgcn_mfma_f32_16x16x32_bf16(a, b_q[ks], acc, 0, 0, 0);
            }
            const float p0 = fexp2(fminf(acc[0], 40.f));
            const float p1 = fexp2(fminf(acc[1], 40.f));
            const float p2 = fexp2(fminf(acc[2], 40.f));
            const float p3 = fexp2(fminf(acc[3], 40.f));
            union { __hip_bfloat162 h[2]; bf16x4 v; } u;
            u.h[0] = __float22bfloat162_rn(make_float2(p0, p1));
            u.h[1] = __float22bfloat162_rn(make_float2(p2, p3));
            *(bf16x4*)&p_lds[wave][l16 * 64 +
                (((nt * 2 + (quad >> 1)) ^ lx) * 8) + (quad & 1) * 4] = u.v;
        }

#pragma unroll
        for (int ks2 = 0; ks2 < 2; ++ks2) {
            short8 pf = *(const short8*)
                &p_lds[wave][l16 * 64 + (((ks2 * 4 + quad) ^ lx) * 8)];
#pragma unroll
            for (int d = 0; d < 4; ++d) {
                short8 vf = *(const short8*)
                    &v_lds[(d * 16 + l16) * 64 + (((ks2 * 4 + quad) ^ lx) * 8)];
                o[d] = __builtin_amdgcn_mfma_f32_16x16x32_bf16(pf, vf, o[d], 0, 0, 0);
            }
            l_acc = __builtin_amdgcn_mfma_f32_16x16x32_bf16(pf, ones, l_acc, 0, 0, 0);
        }
    }

    const int h = bh & 15, bb = bh >> 4;
    float rl[4];
#pragma unroll
    for (int r = 0; r < 4; ++r) rl[r] = 1.f / l_acc[r];
    __syncthreads();
#pragma unroll
    for (int d = 0; d < 4; ++d)
#pragma unroll
        for (int r = 0; r < 4; ++r)
            Ct[(wave * 16 + quad * 4 + r) * 72 + d * 16 + l16] = f2b(o[d][r] * rl[r]);
    __syncthreads();
    {
        const int row = threadIdx.x >> 2, ch = threadIdx.x & 3;
        short8 v0 = *(const short8*)&Ct[row * 72 + ch * 16];
        short8 v1 = *(const short8*)&Ct[row * 72 + ch * 16 + 8];
        short* gp = ctx + ((size_t)(bb * SEQ + qtile * 64 + row)) * DM + h * 64 + ch * 16;
        *(short8*)gp = v0;
        *(short8*)(gp + 8) = v1;
    }
}

// Output GEMM, OPERAND-SWAPPED (C^T): A=Wo rows, B=ctx tokens. Lane fragment =
// 4 consecutive out-cols @ fixed token -> float4 stores + float4 residual loads.
// Tile 64 features x 128 tokens -> 512 blocks = 2/CU.
__global__ __launch_bounds__(256) void gemm_o(const short* __restrict__ C,
        const short* __restrict__ W, const float* __restrict__ bo,
        const float* __restrict__ xin, float* __restrict__ out)
{
    __shared__ short Cs[128 * 32];
    __shared__ short Ws[64 * 32];
    const int tok0 = blockIdx.x * 128, n0 = blockIdx.y * 64;
    const int w = threadIdx.x >> 6, lane = threadIdx.x & 63;
    const int l16 = lane & 15, quad = lane >> 4;
    const int wm = w >> 1, wn = w & 1;     // wm: token half (64), wn: feature half (32)
    const int lr = lane >> 2, lc = (lane & 3) * 8;

    floatx4 acc[2][4];
#pragma unroll
    for (int i = 0; i < 2; ++i)
#pragma unroll
        for (int j = 0; j < 4; ++j) acc[i][j] = (floatx4){0.f, 0.f, 0.f, 0.f};

    for (int kt = 0; kt < DM / 32; ++kt) {
        const int k0 = kt * 32;
        __syncthreads();
        async_copy16(C + (size_t)(tok0 + w * 32 + lr) * DM + k0 + lc,      &Cs[w * 1024]);
        async_copy16(C + (size_t)(tok0 + w * 32 + 16 + lr) * DM + k0 + lc, &Cs[w * 1024 + 512]);
        async_copy16(W + (size_t)(n0 + w * 16 + lr) * DM + k0 + lc,        &Ws[w * 512]);
        __syncthreads();

        short8 af[2], bf[4];
#pragma unroll
        for (int i = 0; i < 2; ++i)
            af[i] = *(const short8*)&Ws[(wn * 32 + i * 16 + l16) * 32 + quad * 8];
#pragma unroll
        for (int j = 0; j < 4; ++j)
            bf[j] = *(const short8*)&Cs[(wm * 64 + j * 16 + l16) * 32 + quad * 8];
#pragma unroll
        for (int i = 0; i < 2; ++i)
#pragma unroll
            for (int j = 0; j < 4; ++j)
                acc[i][j] = __builtin_amdgcn_mfma_f32_16x16x32_bf16(af[i], bf[j], acc[i][j], 0, 0, 0);
    }

#pragma unroll
    for (int i = 0; i < 2; ++i) {
        const int n = n0 + wn * 32 + i * 16 + quad * 4;    // mult of 4
        const floatx4 b4 = *(const floatx4*)&bo[n];
#pragma unroll
        for (int j = 0; j < 4; ++j) {
            const int tok = tok0 + wm * 64 + j * 16 + l16;
            const size_t idx = (size_t)tok * DM + n;
            const floatx4 r4 = *(const floatx4*)&xin[idx];
            floatx4 o4;
            o4.x = acc[i][j][0] + b4.x + r4.x;
            o4.y = acc[i][j][1] + b4.y + r4.y;
            o4.z = acc[i][j][2] + b4.z + r4.z;
            o4.w = acc[i][j][3] + b4.w + r4.w;
            *(floatx4*)&out[idx] = o4;
        }
    }
}

__global__ __launch_bounds__(256) void ln_kernel(float* __restrict__ y,
        const float* __restrict__ gamma, const float* __restrict__ beta)
{
    const int row = blockIdx.x;
    const int t = threadIdx.x;
    const int wave = t >> 6, lane = t & 63;
    const floatx4 v = ((const floatx4*)(y + (size_t)row * DM))[t];
    float s  = v.x + v.y + v.z + v.w;
    float q2 = v.x * v.x + v.y * v.y + v.z * v.z + v.w * v.w;
#pragma unroll
    for (int off = 1; off < 64; off <<= 1) {
        s  += __shfl_xor(s, off);
        q2 += __shfl_xor(q2, off);
    }
    __shared__ float rs[4], rq[4];
    if (lane == 0) { rs[wave] = s; rq[wave] = q2; }
    __syncthreads();
    const float S  = rs[0] + rs[1] + rs[2] + rs[3];
    const float Q2 = rq[0] + rq[1] + rq[2] + rq[3];
    const float mu = S * (1.f / DM);
    float var = Q2 * (1.f / DM) - mu * mu;
    var = fmaxf(var, 0.f);
    const float rstd = rsqrtf(var + 1e-12f);
    const floatx4 g = ((const floatx4*)gamma)[t];
    const floatx4 bt = ((const floatx4*)beta)[t];
    floatx4 o;
    o.x = (v.x - mu) * rstd * g.x + bt.x;
    o.y = (v.y - mu) * rstd * g.y + bt.y;
    o.z = (v.z - mu) * rstd * g.z + bt.z;
    o.w = (v.w - mu) * rstd * g.w + bt.w;
    ((floatx4*)(y + (size_t)row * DM))[t] = o;
}

extern "C" void kernel_launch(void* const* d_in, const int* in_sizes, int n_in,
                              void* d_out, int out_size, void* d_ws, size_t ws_size,
                              hipStream_t stream) {
    const float* x     = (const float*)d_in[0];
    const float* mask  = (const float*)d_in[1];
    const float* Wq    = (const float*)d_in[2];
    const float* bq    = (const float*)d_in[3];
    const float* Wk    = (const float*)d_in[4];
    const float* bk    = (const float*)d_in[5];
    const float* Wv    = (const float*)d_in[6];
    const float* bv    = (const float*)d_in[7];
    const float* Wo    = (const float*)d_in[8];
    const float* bo    = (const float*)d_in[9];
    const float* gamma = (const float*)d_in[10];
    const float* beta  = (const float*)d_in[11];
    float* out = (float*)d_out;

    const size_t NTOK = (size_t)BATCH * SEQ * DM;       // 4M
    const size_t WSZ  = (size_t)DM * DM;                // 1M
    short* xb   = (short*)d_ws;          // 4M shorts
    short* wqkv = xb + NTOK;             // 3M
    short* wob  = wqkv + 3 * WSZ;        // 1M
    short* qw   = wob + WSZ;             // 4M
    short* kw   = qw + NTOK;             // 4M
    short* vw   = kw + NTOK;             // 4M (natural V; aliased as ctx)
    short* vtw  = vw + NTOK;             // 4M (V transposed)
    short* ctxw = vw;
    float* maddg = (float*)(vtw + NTOK); // 4096 floats

    dim3 blk(256);
    cvt_all<<<dim3(8194), blk, 0, stream>>>(x, Wq, Wk, Wv, Wo, mask, xb, wqkv, wob, maddg);
    gemm_qkv<<<dim3(32, 24), blk, 0, stream>>>(xb, wqkv, bq, bk, bv, qw, kw, vw);
    transpose_v<<<dim3(SEQ / 64, BATCH * HEADS), blk, 0, stream>>>(vw, vtw);
    attn_kernel<<<dim3(32 * 32), blk, 0, stream>>>(qw, kw, vtw, maddg, ctxw);
    gemm_o<<<dim3(32, 16), blk, 0, stream>>>(ctxw, wob, bo, x, out);
    ln_kernel<<<BATCH * SEQ, blk, 0, stream>>>(out, gamma, beta);
}

// Round 13
// 221.155 us; speedup vs baseline: 1.0204x; 1.0204x over previous
//
#include <hip/hip_runtime.h>
#include <hip/hip_bf16.h>

#define DM   1024
#define HEADS 16
#define DH    64
#define SEQ  2048
#define BATCH   2
#define LOG2E 1.44269504088896f

typedef __attribute__((ext_vector_type(8))) short short8;
typedef __attribute__((ext_vector_type(4))) short bf16x4;
typedef __attribute__((ext_vector_type(4))) float floatx4;
typedef __attribute__((ext_vector_type(16))) float floatx16;

__device__ __forceinline__ short f2b(float f) {
    union { float f; unsigned u; } v; v.f = f;
    unsigned r = v.u + 0x7FFFu + ((v.u >> 16) & 1u);
    return (short)(r >> 16);
}

#if __has_builtin(__builtin_amdgcn_exp2f)
__device__ __forceinline__ float fexp2(float x) { return __builtin_amdgcn_exp2f(x); }
#else
__device__ __forceinline__ float fexp2(float x) { return exp2f(x); }
#endif

__device__ __forceinline__ void async_copy16(const short* gsrc, short* ldst) {
    __builtin_amdgcn_global_load_lds(
        (const __attribute__((address_space(1))) void*)gsrc,
        (__attribute__((address_space(3))) void*)ldst,
        16, 0, 0);
}

// Fused fp32->bf16 conversion of x, Wq, Wk, Wv, Wo + mask-add table (log2 domain).
__global__ __launch_bounds__(256) void cvt_all(const float* __restrict__ x,
        const float* __restrict__ wq, const float* __restrict__ wk,
        const float* __restrict__ wv, const float* __restrict__ wo,
        const float* __restrict__ mask,
        short* __restrict__ xb, short* __restrict__ wqkv, short* __restrict__ wob,
        float* __restrict__ maddg)
{
    const int b = blockIdx.x;
    if (b >= 8192) {            // mask prep: maddg = (1-mask) * (-1e5 * log2e)
        const int bb = b - 8192;
        const float* mrow = mask + (size_t)bb * SEQ;
        float* mg = maddg + (size_t)bb * SEQ;
#pragma unroll
        for (int i = 0; i < 8; ++i) {
            const int idx = threadIdx.x * 8 + i;
            mg[idx] = (1.f - mrow[idx]) * (-100000.f * LOG2E);
        }
        return;
    }
    const float* src; short* dst; int idx;
    if (b < 4096)      { src = x;  dst = xb;                idx = b; }
    else if (b < 5120) { src = wq; dst = wqkv;              idx = b - 4096; }
    else if (b < 6144) { src = wk; dst = wqkv + (1 << 20);  idx = b - 5120; }
    else if (b < 7168) { src = wv; dst = wqkv + (2 << 20);  idx = b - 6144; }
    else               { src = wo; dst = wob;               idx = b - 7168; }
    const int i = idx * 256 + threadIdx.x;
    floatx4 v = ((const floatx4*)src)[i];
    bf16x4 o;
    o.x = f2b(v.x); o.y = f2b(v.y); o.z = f2b(v.z); o.w = f2b(v.w);
    ((bf16x4*)dst)[i] = o;
}

// Fused QKV GEMM (m97 structure, 128x128 tile, BK=32). B rows: Wq|Wk|Wv.
// Q pre-scaled by 0.125*log2e (exp2-domain softmax). Q/K/V in [b,h,s,dh].
// (round-11 version: scatter epilogue — measured best of 3 variants)
__global__ __launch_bounds__(256) void gemm_qkv(const short* __restrict__ A,
        const short* __restrict__ B,
        const float* __restrict__ bq, const float* __restrict__ bk,
        const float* __restrict__ bv,
        short* __restrict__ qw, short* __restrict__ kw, short* __restrict__ vw)
{
    __shared__ short As[128 * 32];
    __shared__ short Bs[128 * 32];
    const int m0 = blockIdx.x * 128, n0 = blockIdx.y * 128;
    const int w = threadIdx.x >> 6, lane = threadIdx.x & 63;
    const int l16 = lane & 15, quad = lane >> 4;
    const int wm = w >> 1, wn = w & 1;
    const int lr = lane >> 2, lc = (lane & 3) * 8;

    floatx4 acc[4][4];
#pragma unroll
    for (int i = 0; i < 4; ++i)
#pragma unroll
        for (int j = 0; j < 4; ++j) acc[i][j] = (floatx4){0.f, 0.f, 0.f, 0.f};

    for (int kt = 0; kt < DM / 32; ++kt) {
        const int k0 = kt * 32;
        __syncthreads();
        async_copy16(A + (size_t)(m0 + w * 32 + lr) * DM + k0 + lc,      &As[w * 1024]);
        async_copy16(A + (size_t)(m0 + w * 32 + 16 + lr) * DM + k0 + lc, &As[w * 1024 + 512]);
        async_copy16(B + (size_t)(n0 + w * 32 + lr) * DM + k0 + lc,      &Bs[w * 1024]);
        async_copy16(B + (size_t)(n0 + w * 32 + 16 + lr) * DM + k0 + lc, &Bs[w * 1024 + 512]);
        __syncthreads();

        short8 af[4], bf[4];
#pragma unroll
        for (int i = 0; i < 4; ++i)
            af[i] = *(const short8*)&As[(wm * 64 + i * 16 + l16) * 32 + quad * 8];
#pragma unroll
        for (int j = 0; j < 4; ++j)
            bf[j] = *(const short8*)&Bs[(wn * 64 + j * 16 + l16) * 32 + quad * 8];
#pragma unroll
        for (int i = 0; i < 4; ++i)
#pragma unroll
            for (int j = 0; j < 4; ++j)
                acc[i][j] = __builtin_amdgcn_mfma_f32_16x16x32_bf16(af[i], bf[j], acc[i][j], 0, 0, 0);
    }

    const int m_base = m0 + wm * 64 + quad * 4;
#pragma unroll
    for (int j = 0; j < 4; ++j) {
        const int nb = n0 + wn * 64 + j * 16;
        const int t = nb >> 10;
        const int nn = (nb & 1023) + l16;
        const int h = nn >> 6, dh = nn & 63;
        const float* bias = (t == 0) ? bq : (t == 1) ? bk : bv;
        short* dst = (t == 0) ? qw : (t == 1) ? kw : vw;
        const float mulf = (t == 0) ? (0.125f * LOG2E) : 1.0f;
        const float bvv = bias[nn];
#pragma unroll
        for (int i = 0; i < 4; ++i)
#pragma unroll
            for (int r = 0; r < 4; ++r) {
                const int m = m_base + i * 16 + r;
                const int b = m >> 11, s = m & (SEQ - 1);
                dst[(((size_t)(b * HEADS + h)) * SEQ + s) * DH + dh] =
                    f2b((acc[i][j][r] + bvv) * mulf);
            }
    }
}

// v [b,h,s,dh] -> vt [b,h,dh,s], 64x64 LDS tiles (coalesced both sides)
__global__ __launch_bounds__(256) void transpose_v(const short* __restrict__ v,
                                                   short* __restrict__ vt)
{
    __shared__ short tl[64][72];
    const int st = blockIdx.x;
    const int bh = blockIdx.y;
    const int t = threadIdx.x;
    const int row = t >> 2, off = (t & 3) * 16;
    const short* vp = v + ((size_t)bh * SEQ + st * 64 + row) * DH + off;
    *(short8*)&tl[row][off]     = *(const short8*)vp;
    *(short8*)&tl[row][off + 8] = *(const short8*)(vp + 8);
    __syncthreads();
    short8 o0, o1;
#pragma unroll
    for (int j = 0; j < 8; ++j) { o0[j] = tl[off + j][row]; o1[j] = tl[off + 8 + j][row]; }
    short* op = vt + ((size_t)bh * DH + row) * SEQ + st * 64 + off;
    *(short8*)op = o0;
    *(short8*)(op + 8) = o1;
}

// Flash attention, 32x32x16 MFMA formulation (halves LDS-read traffic per FLOP).
// S^T = K Q^T per 32x32 tile: wave w -> keys (w&1)*32.., qrows (w>>1)*32..
// PV: O^T[dh][qrow]: wave w -> dh (w&1)*32.., qrows (w>>1)*32.. ; P crosses the
// qrow-pair of waves via p_lds (3rd barrier). NO-MAX softmax (exp2(min(s,40))).
// l via LDS partial table. XCD-swizzled grid. xor-swizzled packed LDS.
// Layouts: A/B 32x32x16: m(n)=lane&31, k=8*(lane>>5)+j. C/D: col=lane&31,
// row=(reg&3)+8*(reg>>2)+4*(lane>>5)  [m74/m101-verified].
__global__ __launch_bounds__(256) void attn_kernel(const short* __restrict__ q,
        const short* __restrict__ k, const short* __restrict__ vt,
        const float* __restrict__ maddg, short* __restrict__ ctx)
{
    const int id    = blockIdx.x;
    const int qtile = id >> 5;             // id = qtile*32 + bh
    const int bh    = id & 31;
    const int bidx  = bh >> 4;
    const int wave = threadIdx.x >> 6, lane = threadIdx.x & 63;
    const int l32 = lane & 31, half = lane >> 5;
    const int kw = wave & 1, qw = wave >> 1;   // S^T: keys kw*32.., qrows qw*32..
                                               // PV: dh kw*32.., qrows qw*32..

    __shared__ short k_lds[64 * 64];       // [key][dh] packed+swizzled
    __shared__ short v_lds[64 * 64];       // [dh][key] packed+swizzled
    __shared__ short p_lds[64 * 64];       // [qrow][key] packed+swizzled
    __shared__ float l_lds[4 * 64];        // [part][qrow] row-sum partials
    __shared__ short Ct[64 * 72];          // ctx epilogue staging

    const short* kbase0 = k  + (size_t)bh * SEQ * DH;
    const short* vbase0 = vt + (size_t)bh * DH * SEQ;
    const float* mrow   = maddg + (size_t)bidx * SEQ;

    // Q B-frags: B[n=qrow=l32][k=dh = kk*16 + half*8 + j]
    const int qrow = qtile * 64 + qw * 32 + l32;
    const short* qbase = q + ((size_t)bh * SEQ + qrow) * DH;
    short8 b_q[4];
#pragma unroll
    for (int kk = 0; kk < 4; ++kk)
        b_q[kk] = *(const short8*)(qbase + kk * 16 + half * 8);

    floatx16 oacc;
#pragma unroll
    for (int r = 0; r < 16; ++r) oacc[r] = 0.f;
    float l_run = 0.f;

    // staging geometry: 512 chunks/tile, 256 threads -> 2 chunks/thread/array
    int srw[2], gg[2];
#pragma unroll
    for (int i = 0; i < 2; ++i) {
        const int slot = i * 256 + wave * 64 + lane;
        srw[i] = slot >> 3;
        gg[i]  = (slot & 7) ^ (srw[i] & 7);
    }

    const int prow = qw * 32 + l32;        // this lane's qrow (local 0..63), S^T & PV

    for (int kt = 0; kt < SEQ / 64; ++kt) {
        __syncthreads();                   // B1: prev-iter v/p/l reads complete
        {   // stage K,V via global_load_lds; slot -> global chunk xor-permuted
            const short* kbase = kbase0 + (size_t)(kt * 64) * DH;
            const short* vbase = vbase0 + kt * 64;
#pragma unroll
            for (int i = 0; i < 2; ++i) {
                async_copy16(kbase + srw[i] * DH + gg[i] * 8,
                             &k_lds[(i * 256 + wave * 64) * 8]);
                async_copy16(vbase + (size_t)srw[i] * SEQ + gg[i] * 8,
                             &v_lds[(i * 256 + wave * 64) * 8]);
            }
        }
        // mask C-init loads: key = kt*64 + kw*32 + 8g + 4*half + r
        floatx4 md[4];
#pragma unroll
        for (int g = 0; g < 4; ++g)
            md[g] = *(const floatx4*)&mrow[kt * 64 + kw * 32 + 8 * g + 4 * half];
        __syncthreads();                   // B2: staging drained

        // S^T = K Q^T (log2 domain), 4 MFMA 32x32x16, C init = mask
        floatx16 s;
#pragma unroll
        for (int g = 0; g < 4; ++g)
#pragma unroll
            for (int r = 0; r < 4; ++r) s[g * 4 + r] = md[g][r];
        {
            const int krow = kw * 32 + l32;
            const int ksw = krow & 7;
#pragma unroll
            for (int kk = 0; kk < 4; ++kk) {
                const int c = kk * 2 + half;
                short8 a = *(const short8*)&k_lds[krow * 64 + ((c ^ ksw) * 8)];
                s = __builtin_amdgcn_mfma_f32_32x32x16_bf16(a, b_q[kk], s, 0, 0, 0);
            }
        }

        // p = exp2(min(s,40)); partial row-sum; packed stores to p_lds [qrow][key]
        float lsum = 0.f;
        const int psw = prow & 7;
#pragma unroll
        for (int g = 0; g < 4; ++g) {
            const float p0 = fexp2(fminf(s[g * 4 + 0], 40.f));
            const float p1 = fexp2(fminf(s[g * 4 + 1], 40.f));
            const float p2 = fexp2(fminf(s[g * 4 + 2], 40.f));
            const float p3 = fexp2(fminf(s[g * 4 + 3], 40.f));
            lsum += (p0 + p1) + (p2 + p3);
            union { __hip_bfloat162 h[2]; bf16x4 v; } u;
            u.h[0] = __float22bfloat162_rn(make_float2(p0, p1));
            u.h[1] = __float22bfloat162_rn(make_float2(p2, p3));
            const int c = kw * 4 + g;      // chunk of key offset kw*32+8g
            *(bf16x4*)&p_lds[prow * 64 + ((c ^ psw) * 8) + 4 * half] = u.v;
        }
        l_lds[(kw * 2 + half) * 64 + prow] = lsum;
        __syncthreads();                   // B3: P + l partials visible

        // l accumulate for owned qrow (no-max softmax: additive)
        l_run += l_lds[0 * 64 + prow] + l_lds[1 * 64 + prow]
               + l_lds[2 * 64 + prow] + l_lds[3 * 64 + prow];

        // O^T += V^T P^T : A=V^T[dh][key], B=P[qrow][key], 4 MFMA 32x32x16
        {
            const int vrow = kw * 32 + l32;    // dh row
            const int vsw = vrow & 7;
#pragma unroll
            for (int kk = 0; kk < 4; ++kk) {
                const int c = kk * 2 + half;
                short8 av = *(const short8*)&v_lds[vrow * 64 + ((c ^ vsw) * 8)];
                short8 bp = *(const short8*)&p_lds[prow * 64 + ((c ^ psw) * 8)];
                oacc = __builtin_amdgcn_mfma_f32_32x32x16_bf16(av, bp, oacc, 0, 0, 0);
            }
        }
    }

    // epilogue: O^T[dh][qrow] / l -> Ct[qrow][dh] -> coalesced global stores
    const int h = bh & 15, bb = bh >> 4;
    const float rl = 1.f / l_run;
#pragma unroll
    for (int g = 0; g < 4; ++g) {
        bf16x4 p;
        p.x = f2b(oacc[g * 4 + 0] * rl);
        p.y = f2b(oacc[g * 4 + 1] * rl);
        p.z = f2b(oacc[g * 4 + 2] * rl);
        p.w = f2b(oacc[g * 4 + 3] * rl);
        const int dh = kw * 32 + 8 * g + 4 * half;   // row=(reg&3)+8g+4*half
        *(bf16x4*)&Ct[prow * 72 + dh] = p;
    }
    __syncthreads();
    {
        const int row = threadIdx.x >> 2, ch = threadIdx.x & 3;
        short8 v0 = *(const short8*)&Ct[row * 72 + ch * 16];
        short8 v1 = *(const short8*)&Ct[row * 72 + ch * 16 + 8];
        short* gp = ctx + ((size_t)(bb * SEQ + qtile * 64 + row)) * DM + h * 64 + ch * 16;
        *(short8*)gp = v0;
        *(short8*)(gp + 8) = v1;
    }
}

// Output GEMM + bias + residual (fp32 out into d_out). 128x64 tile, 2 blocks/CU.
// (round-11 version)
__global__ __launch_bounds__(256) void gemm_o(const short* __restrict__ A,
        const short* __restrict__ B, const float* __restrict__ bo,
        const float* __restrict__ xin, float* __restrict__ out)
{
    __shared__ short As[128 * 32];
    __shared__ short Bs[64 * 32];
    const int m0 = blockIdx.x * 128, n0 = blockIdx.y * 64;
    const int w = threadIdx.x >> 6, lane = threadIdx.x & 63;
    const int l16 = lane & 15, quad = lane >> 4;
    const int wm = w >> 1, wn = w & 1;     // wave: 64 rows x 32 cols

    floatx4 acc[4][2];
#pragma unroll
    for (int i = 0; i < 4; ++i)
#pragma unroll
        for (int j = 0; j < 2; ++j) acc[i][j] = (floatx4){0.f, 0.f, 0.f, 0.f};

    const int c0 = w * 64 + lane;

    for (int kt = 0; kt < DM / 32; ++kt) {
        const int k0 = kt * 32;
        __syncthreads();
        {
            const int ra0 = c0 >> 2,          ca0 = (c0 & 3) * 8;
            const int ra1 = (256 + c0) >> 2,  ca1 = (c0 & 3) * 8;
            async_copy16(A + (size_t)(m0 + ra0) * DM + k0 + ca0, &As[(w * 64) * 8]);
            async_copy16(A + (size_t)(m0 + ra1) * DM + k0 + ca1, &As[(256 + w * 64) * 8]);
            const int rb = c0 >> 2, cb = (c0 & 3) * 8;
            async_copy16(B + (size_t)(n0 + rb) * DM + k0 + cb,   &Bs[(w * 64) * 8]);
        }
        __syncthreads();

        short8 af[4], bf[2];
#pragma unroll
        for (int i = 0; i < 4; ++i)
            af[i] = *(const short8*)&As[(wm * 64 + i * 16 + l16) * 32 + quad * 8];
#pragma unroll
        for (int j = 0; j < 2; ++j)
            bf[j] = *(const short8*)&Bs[(wn * 32 + j * 16 + l16) * 32 + quad * 8];
#pragma unroll
        for (int i = 0; i < 4; ++i)
#pragma unroll
            for (int j = 0; j < 2; ++j)
                acc[i][j] = __builtin_amdgcn_mfma_f32_16x16x32_bf16(af[i], bf[j], acc[i][j], 0, 0, 0);
    }

    const int m_base = m0 + wm * 64 + quad * 4;
#pragma unroll
    for (int j = 0; j < 2; ++j) {
        const int n = n0 + wn * 32 + j * 16 + l16;
        const float bvv = bo[n];
#pragma unroll
        for (int i = 0; i < 4; ++i)
#pragma unroll
            for (int r = 0; r < 4; ++r) {
                const int m = m_base + i * 16 + r;
                const size_t idx = (size_t)m * DM + n;
                out[idx] = acc[i][j][r] + bvv + xin[idx];
            }
    }
}

__global__ __launch_bounds__(256) void ln_kernel(float* __restrict__ y,
        const float* __restrict__ gamma, const float* __restrict__ beta)
{
    const int row = blockIdx.x;
    const int t = threadIdx.x;
    const int wave = t >> 6, lane = t & 63;
    const floatx4 v = ((const floatx4*)(y + (size_t)row * DM))[t];
    float s  = v.x + v.y + v.z + v.w;
    float q2 = v.x * v.x + v.y * v.y + v.z * v.z + v.w * v.w;
#pragma unroll
    for (int off = 1; off < 64; off <<= 1) {
        s  += __shfl_xor(s, off);
        q2 += __shfl_xor(q2, off);
    }
    __shared__ float rs[4], rq[4];
    if (lane == 0) { rs[wave] = s; rq[wave] = q2; }
    __syncthreads();
    const float S  = rs[0] + rs[1] + rs[2] + rs[3];
    const float Q2 = rq[0] + rq[1] + rq[2] + rq[3];
    const float mu = S * (1.f / DM);
    float var = Q2 * (1.f / DM) - mu * mu;
    var = fmaxf(var, 0.f);
    const float rstd = rsqrtf(var + 1e-12f);
    const floatx4 g = ((const floatx4*)gamma)[t];
    const floatx4 bt = ((const floatx4*)beta)[t];
    floatx4 o;
    o.x = (v.x - mu) * rstd * g.x + bt.x;
    o.y = (v.y - mu) * rstd * g.y + bt.y;
    o.z = (v.z - mu) * rstd * g.z + bt.z;
    o.w = (v.w - mu) * rstd * g.w + bt.w;
    ((floatx4*)(y + (size_t)row * DM))[t] = o;
}

extern "C" void kernel_launch(void* const* d_in, const int* in_sizes, int n_in,
                              void* d_out, int out_size, void* d_ws, size_t ws_size,
                              hipStream_t stream) {
    const float* x     = (const float*)d_in[0];
    const float* mask  = (const float*)d_in[1];
    const float* Wq    = (const float*)d_in[2];
    const float* bq    = (const float*)d_in[3];
    const float* Wk    = (const float*)d_in[4];
    const float* bk    = (const float*)d_in[5];
    const float* Wv    = (const float*)d_in[6];
    const float* bv    = (const float*)d_in[7];
    const float* Wo    = (const float*)d_in[8];
    const float* bo    = (const float*)d_in[9];
    const float* gamma = (const float*)d_in[10];
    const float* beta  = (const float*)d_in[11];
    float* out = (float*)d_out;

    const size_t NTOK = (size_t)BATCH * SEQ * DM;       // 4M
    const size_t WSZ  = (size_t)DM * DM;                // 1M
    short* xb   = (short*)d_ws;          // 4M shorts
    short* wqkv = xb + NTOK;             // 3M
    short* wob  = wqkv + 3 * WSZ;        // 1M
    short* qw   = wob + WSZ;             // 4M
    short* kw   = qw + NTOK;             // 4M
    short* vw   = kw + NTOK;             // 4M (natural V; aliased as ctx)
    short* vtw  = vw + NTOK;             // 4M (V transposed)
    short* ctxw = vw;
    float* maddg = (float*)(vtw + NTOK); // 4096 floats

    dim3 blk(256);
    cvt_all<<<dim3(8194), blk, 0, stream>>>(x, Wq, Wk, Wv, Wo, mask, xb, wqkv, wob, maddg);
    gemm_qkv<<<dim3(32, 24), blk, 0, stream>>>(xb, wqkv, bq, bk, bv, qw, kw, vw);
    transpose_v<<<dim3(SEQ / 64, BATCH * HEADS), blk, 0, stream>>>(vw, vtw);
    attn_kernel<<<dim3(32 * 32), blk, 0, stream>>>(qw, kw, vtw, maddg, ctxw);
    gemm_o<<<dim3(32, 16), blk, 0, stream>>>(ctxw, wob, bo, x, out);
    ln_kernel<<<BATCH * SEQ, blk, 0, stream>>>(out, gamma, beta);
}